// Round 11
// baseline (55.269 us; speedup 1.0000x reference)
//
#include <hip/hip_runtime.h>

// affine_grid + grid_sample (bilinear, zeros, align_corners=False)
// N=64, C=3, H=345, W=456, fp32.
// Round 11: 64x16 tile, 1024-thread block, 1 px/thread. Each wave spans 64
//           consecutive columns -> LDS reads are 2 lanes/bank (free), stores
//           are 256B contiguous per wave. Branch-free clamped staging.
constexpr int N_ = 64, C_ = 3, H_ = 345, W_ = 456;
constexpr int HW_ = H_ * W_;

constexpr int TW = 64, TH = 16;                // output tile: 1024 px, 1 px/thread
constexpr int TX = 8, TY = 22;                 // ceil(456/64), ceil(345/16)
constexpr int TILES = TX * TY;                 // 176
constexpr int CCAP = 96;                       // staged cols / LDS row stride (24 float4; 96%32==0)
constexpr int RCAP = 40;                       // staged rows
constexpr int CH_STRIDE = RCAP * CCAP;         // 3840 floats/channel (46080 B total)
constexpr int SLOTS = (CCAP / 4) * RCAP;       // 960 float4 slots per channel

__device__ __forceinline__ void make_win(
    int w0, int h0, float Ax, float Bx, float Cx, float Ay, float By, float Cy,
    int& xa_out, int& ylo_out)
{
    float ws = (float)w0, we = (float)min(w0 + TW - 1, W_ - 1);
    float hs = (float)h0, he = (float)min(h0 + TH - 1, H_ - 1);
    float xw0 = ws * Ax, xw1 = we * Ax;
    float xh0 = hs * Bx, xh1 = he * Bx;
    float minix = Cx + fminf(xw0, xw1) + fminf(xh0, xh1);
    float maxix = Cx + fmaxf(xw0, xw1) + fmaxf(xh0, xh1);
    float yw0 = ws * Ay, yw1 = we * Ay;
    float yh0 = hs * By, yh1 = he * By;
    float miniy = Cy + fminf(yw0, yw1) + fminf(yh0, yh1);
    float maxiy = Cy + fmaxf(yw0, yw1) + fmaxf(yh0, yh1);

    int x_lo = (int)floorf(minix) - 1, x_hi = (int)floorf(maxix) + 2;
    int y_lo = (int)floorf(miniy) - 1, y_hi = (int)floorf(maxiy) + 2;

    int xa = x_lo & ~3;                        // align down (ok for negatives)
    int cols4 = (x_hi - xa + 4) >> 2;
    if (cols4 > CCAP / 4) xa += ((cols4 - CCAP / 4) >> 1) << 2;   // center oversized
    int rows = y_hi - y_lo + 1;
    if (rows > RCAP) y_lo += (rows - RCAP) >> 1;

    // clamp fully inside the image: staging is branch-free valid float4 loads;
    // pixels whose corners leave the window use the per-pixel global fallback.
    xa   = max(0, min(xa,   W_ - CCAP));       // 360, stays 4-aligned
    y_lo = max(0, min(y_lo, H_ - RCAP));       // 305
    xa_out = xa; ylo_out = y_lo;
}

__global__ __launch_bounds__(1024) void gs_tiled(
    const float* __restrict__ x,      // [N,3,H,W]
    const float* __restrict__ theta,  // [N,2,3]
    float* __restrict__ out)          // [N,3,H,W]
{
    __shared__ float lds[3 * CH_STRIDE];       // 46080 B -> 2 blocks/CU (2048 thr = 100%)

    // XCD-affine: batch n -> XCD n%8 only (grid divisible by 8).
    int b    = blockIdx.x;
    int xcd  = b & 7;
    int i    = b >> 3;                 // 0..1407
    int bg   = i / TILES;              // 0..7
    int tile = i - bg * TILES;
    int n    = xcd + 8 * bg;

    int ty = tile / TX;
    int tx = tile - ty * TX;
    int w0 = tx * TW, h0 = ty * TH;

    const float* t = theta + n * 6;
    float t00 = t[0], t01 = t[1], t02 = t[2];
    float t10 = t[3], t11 = t[4], t12 = t[5];

    const float halfW = 0.5f * (float)W_, cW = 0.5f * (float)(W_ - 1);
    const float halfH = 0.5f * (float)H_, cH = 0.5f * (float)(H_ - 1);
    const float startx = -(1.0f - 1.0f / (float)W_);
    const float starty = -(1.0f - 1.0f / (float)H_);

    // Linear map: ix = Ax*w + Bx*h + Cx ; iy = Ay*w + By*h + Cy
    float Ax = t00;
    float Bx = t01 * ((float)W_ / (float)H_);
    float Cx = fmaf(startx, t00, fmaf(starty, t01, t02)) * halfW + cW;
    float Ay = t10 * ((float)H_ / (float)W_);
    float By = t11;
    float Cy = fmaf(startx, t10, fmaf(starty, t11, t12)) * halfH + cH;

    const float* xn = x + (size_t)n * 3 * HW_;
    float* on = out + (size_t)n * 3 * HW_;

    int tid = threadIdx.x;

    int cxa, cylo;
    make_win(w0, h0, Ax, Bx, Cx, Ay, By, Cy, cxa, cylo);

    // ---- branch-free staging: flat float4 slots, window always inside image ----
    if (tid < SLOTS) {                         // 960 of 1024 threads stage one slot
        int r1 = tid / 24, j1 = tid - 24 * r1;
        const float* g1 = xn + (size_t)(cylo + r1) * W_ + cxa + 4 * j1;
        float4 a0 = *(const float4*)(g1);
        float4 a1 = *(const float4*)(g1 + HW_);
        float4 a2 = *(const float4*)(g1 + 2 * HW_);
        float* d1 = lds + 4 * tid;
        *(float4*)(d1)                 = a0;
        *(float4*)(d1 + CH_STRIDE)     = a1;
        *(float4*)(d1 + 2 * CH_STRIDE) = a2;
    }
    __syncthreads();

    // ---- compute: 1 px/thread, wave = 64 consecutive cols of one row ----
    int w = w0 + (tid & 63), h = h0 + (tid >> 6);
    if (w >= W_ || h >= H_) return;            // after the only barrier

    float fw = (float)w, fh = (float)h;
    float ix = fmaf(fw, Ax, fmaf(fh, Bx, Cx));
    float iy = fmaf(fw, Ay, fmaf(fh, By, Cy));

    float xf = floorf(ix), yf = floorf(iy);
    float fx = ix - xf,    fy = iy - yf;
    int   X0 = (int)xf,    Y0 = (int)yf;

    int lc = X0 - cxa, lr = Y0 - cylo;
    bool in = (unsigned)lc < (unsigned)(CCAP - 1) && (unsigned)lr < (unsigned)(RCAP - 1);

    size_t o = (size_t)h * W_ + w;

    if (__builtin_expect(in, 1)) {
        const float* p = lds + lr * CCAP + lc;
        // channel 0
        {
            float p00 = p[0], p10 = p[1], p01 = p[CCAP], p11 = p[CCAP + 1];
            float tp = fmaf(fx, p10 - p00, p00);
            float bt = fmaf(fx, p11 - p01, p01);
            on[o] = fmaf(fy, bt - tp, tp);
        }
        // channel 1
        {
            float p00 = p[CH_STRIDE],        p10 = p[CH_STRIDE + 1];
            float p01 = p[CH_STRIDE + CCAP], p11 = p[CH_STRIDE + CCAP + 1];
            float tp = fmaf(fx, p10 - p00, p00);
            float bt = fmaf(fx, p11 - p01, p01);
            on[o + HW_] = fmaf(fy, bt - tp, tp);
        }
        // channel 2
        {
            float p00 = p[2 * CH_STRIDE],        p10 = p[2 * CH_STRIDE + 1];
            float p01 = p[2 * CH_STRIDE + CCAP], p11 = p[2 * CH_STRIDE + CCAP + 1];
            float tp = fmaf(fx, p10 - p00, p00);
            float bt = fmaf(fx, p11 - p01, p01);
            on[o + 2 * HW_] = fmaf(fy, bt - tp, tp);
        }
    } else {
        // rare: corner(s) outside staged window (incl. out-of-image): direct gather
        float gx1 = 1.0f - fx, gy1 = 1.0f - fy;
        float w00 = gx1 * gy1, w10 = fx * gy1, w01 = gx1 * fy, w11 = fx * fy;
        float a0 = 0.0f, a1 = 0.0f, a2 = 0.0f;
#define CORNG(xi, yi, wt)                                                     \
        if ((unsigned)(xi) < (unsigned)W_ && (unsigned)(yi) < (unsigned)H_) { \
            int off = (yi) * W_ + (xi);                                       \
            a0 += xn[off] * (wt);                                             \
            a1 += xn[HW_ + off] * (wt);                                       \
            a2 += xn[2 * HW_ + off] * (wt);                                   \
        }
        CORNG(X0,     Y0,     w00)
        CORNG(X0 + 1, Y0,     w10)
        CORNG(X0,     Y0 + 1, w01)
        CORNG(X0 + 1, Y0 + 1, w11)
#undef CORNG
        on[o]           = a0;
        on[o + HW_]     = a1;
        on[o + 2 * HW_] = a2;
    }
}

extern "C" void kernel_launch(void* const* d_in, const int* in_sizes, int n_in,
                              void* d_out, int out_size, void* d_ws, size_t ws_size,
                              hipStream_t stream) {
    const float* x     = (const float*)d_in[0];
    const float* theta = (const float*)d_in[1];
    float* out = (float*)d_out;

    int blocks = N_ * TILES;   // 11264, divisible by 8
    gs_tiled<<<blocks, 1024, 0, stream>>>(x, theta, out);
}

// Round 12
// 44.885 us; speedup vs baseline: 1.2314x; 1.2314x over previous
//
#include <hip/hip_runtime.h>

// affine_grid + grid_sample (bilinear, zeros, align_corners=False)
// N=64, C=3, H=345, W=456, fp32.
// Round 12: round-9 structure, but the staged window is the UNCLAMPED bbox
//           (zero-filled outside the image) -> per-pixel window checks and the
//           per-pixel fallback are deleted; capacity overflow is a rare
//           block-uniform wholesale gather path.
constexpr int N_ = 64, C_ = 3, H_ = 345, W_ = 456;
constexpr int HW_ = H_ * W_;

constexpr int TW = 32, TH = 16;                // output tile: 512 px, 2 px/thread
constexpr int TX = 15, TY = 22;
constexpr int TILES = TX * TY;                 // 330
constexpr int CCAP = 52;                       // staged cols / LDS row stride (13 float4)
constexpr int RCAP = 28;                       // staged rows
constexpr int CJ   = 13;                       // float4 columns
constexpr int CH_STRIDE = RCAP * CCAP;         // 1456 floats/channel (17472 B total)
constexpr int SLOTS = CJ * RCAP;               // 364 float4 slots per channel

typedef __attribute__((ext_vector_type(2))) float f32x2;

__global__ __launch_bounds__(256) void gs_tiled(
    const float* __restrict__ x,      // [N,3,H,W]
    const float* __restrict__ theta,  // [N,2,3]
    float* __restrict__ out)          // [N,3,H,W]
{
    __shared__ float lds[3 * CH_STRIDE];       // 17472 B -> 8 blocks/CU

    // XCD-affine: batch n -> XCD n%8 only (grid divisible by 8).
    int b    = blockIdx.x;
    int xcd  = b & 7;
    int i    = b >> 3;
    int bg   = i / TILES;
    int tile = i - bg * TILES;
    int n    = xcd + 8 * bg;

    int ty = tile / TX;
    int tx = tile - ty * TX;
    int w0 = tx * TW, h0 = ty * TH;

    const float* t = theta + n * 6;
    float t00 = t[0], t01 = t[1], t02 = t[2];
    float t10 = t[3], t11 = t[4], t12 = t[5];

    const float halfW = 0.5f * (float)W_, cW = 0.5f * (float)(W_ - 1);
    const float halfH = 0.5f * (float)H_, cH = 0.5f * (float)(H_ - 1);
    const float startx = -(1.0f - 1.0f / (float)W_);
    const float starty = -(1.0f - 1.0f / (float)H_);

    // Linear map: ix = Ax*w + Bx*h + Cx ; iy = Ay*w + By*h + Cy
    float Ax = t00;
    float Bx = t01 * ((float)W_ / (float)H_);
    float Cx = fmaf(startx, t00, fmaf(starty, t01, t02)) * halfW + cW;
    float Ay = t10 * ((float)H_ / (float)W_);
    float By = t11;
    float Cy = fmaf(startx, t10, fmaf(starty, t11, t12)) * halfH + cH;

    // ---- exact source bbox over the clamped tile (linear map, monotone) ----
    float ws = (float)w0, we = (float)min(w0 + TW - 1, W_ - 1);
    float hs = (float)h0, he = (float)min(h0 + TH - 1, H_ - 1);

    float xw0 = ws * Ax, xw1 = we * Ax;
    float xh0 = hs * Bx, xh1 = he * Bx;
    float minix = Cx + fminf(xw0, xw1) + fminf(xh0, xh1);
    float maxix = Cx + fmaxf(xw0, xw1) + fmaxf(xh0, xh1);

    float yw0 = ws * Ay, yw1 = we * Ay;
    float yh0 = hs * By, yh1 = he * By;
    float miniy = Cy + fminf(yw0, yw1) + fminf(yh0, yh1);
    float maxiy = Cy + fmaxf(yw0, yw1) + fmaxf(yh0, yh1);

    // +-1 margin (fp slack); +1 more on hi for bilinear's +1 corner
    int x_lo = (int)floorf(minix) - 1, x_hi = (int)floorf(maxix) + 2;
    int y_lo = (int)floorf(miniy) - 1, y_hi = (int)floorf(maxiy) + 2;

    int xa    = x_lo & ~3;                     // align down (ok for negatives)
    int cols4 = (x_hi - xa + 4) >> 2;
    int rows  = y_hi - y_lo + 1;
    bool fits = (cols4 <= CJ) && (rows <= RCAP);   // block-uniform

    const float* xn = x + (size_t)n * 3 * HW_;
    float* on = out + (size_t)n * 3 * HW_;

    int tid = threadIdx.x;
    int tw = (tid & 15) * 2, th = tid >> 4;
    int w = w0 + tw, h = h0 + th;

    if (__builtin_expect(fits, 1)) {
        // ---- stage full CCAPxRCAP window at (xa, y_lo); zero-fill OOI ----
        bool interior = (xa >= 0) && (xa + CCAP <= W_) &&
                        (y_lo >= 0) && (y_lo + RCAP <= H_);
        if (interior) {
            // branch-free float4 staging (round-9 path, verbatim)
            int s1 = tid;
            int r1 = s1 / 13, j1 = s1 - 13 * r1;
            const float* g1 = xn + (size_t)(y_lo + r1) * W_ + xa + 4 * j1;
            float4 a0 = *(const float4*)(g1);
            float4 a1 = *(const float4*)(g1 + HW_);
            float4 a2 = *(const float4*)(g1 + 2 * HW_);
            float* d1 = lds + 4 * s1;
            *(float4*)(d1)                 = a0;
            *(float4*)(d1 + CH_STRIDE)     = a1;
            *(float4*)(d1 + 2 * CH_STRIDE) = a2;

            int s2 = tid + 256;
            if (s2 < SLOTS) {                  // tid < 108
                int r2 = s2 / 13, j2 = s2 - 13 * r2;
                const float* g2 = xn + (size_t)(y_lo + r2) * W_ + xa + 4 * j2;
                float4 b0 = *(const float4*)(g2);
                float4 b1 = *(const float4*)(g2 + HW_);
                float4 b2 = *(const float4*)(g2 + 2 * HW_);
                float* d2 = lds + 4 * s2;
                *(float4*)(d2)                 = b0;
                *(float4*)(d2 + CH_STRIDE)     = b1;
                *(float4*)(d2 + 2 * CH_STRIDE) = b2;
            }
        } else {
            // edge staging: per-texel predicated zero-fill (block-uniform branch)
            #pragma unroll 1
            for (int s = tid; s < SLOTS; s += 256) {
                int r = s / 13, j = s - 13 * r;
                int y = y_lo + r;
                int xc = xa + 4 * j;
                bool yok = (unsigned)y < (unsigned)H_;
                bool ok0 = yok && (unsigned)(xc + 0) < (unsigned)W_;
                bool ok1 = yok && (unsigned)(xc + 1) < (unsigned)W_;
                bool ok2 = yok && (unsigned)(xc + 2) < (unsigned)W_;
                bool ok3 = yok && (unsigned)(xc + 3) < (unsigned)W_;
                const float* row = xn + (size_t)y * W_ + xc;
                float4 v0, v1, v2;
                v0.x = ok0 ? row[0] : 0.0f;
                v0.y = ok1 ? row[1] : 0.0f;
                v0.z = ok2 ? row[2] : 0.0f;
                v0.w = ok3 ? row[3] : 0.0f;
                v1.x = ok0 ? row[HW_ + 0] : 0.0f;
                v1.y = ok1 ? row[HW_ + 1] : 0.0f;
                v1.z = ok2 ? row[HW_ + 2] : 0.0f;
                v1.w = ok3 ? row[HW_ + 3] : 0.0f;
                v2.x = ok0 ? row[2 * HW_ + 0] : 0.0f;
                v2.y = ok1 ? row[2 * HW_ + 1] : 0.0f;
                v2.z = ok2 ? row[2 * HW_ + 2] : 0.0f;
                v2.w = ok3 ? row[2 * HW_ + 3] : 0.0f;
                float* d = lds + 4 * s;
                *(float4*)(d)                 = v0;
                *(float4*)(d + CH_STRIDE)     = v1;
                *(float4*)(d + 2 * CH_STRIDE) = v2;
            }
        }
        __syncthreads();

        if (w >= W_ || h >= H_) return;        // after the only barrier

        // ---- compute: NO window checks (bbox guarantees containment) ----
        float fw = (float)w, fh = (float)h;
        float hx  = fmaf(fh, Bx, Cx), hy = fmaf(fh, By, Cy);
        float ixA = fmaf(fw, Ax, hx), iyA = fmaf(fw, Ay, hy);
        float ixB = ixA + Ax,         iyB = iyA + Ay;

        float xfA = floorf(ixA), yfA = floorf(iyA);
        float fxA = ixA - xfA,   fyA = iyA - yfA;
        float xfB = floorf(ixB), yfB = floorf(iyB);
        float fxB = ixB - xfB,   fyB = iyB - yfB;

        int lcA = (int)xfA - xa, lrA = (int)yfA - y_lo;
        int lcB = (int)xfB - xa, lrB = (int)yfB - y_lo;

        const float* pA = lds + lrA * CCAP + lcA;
        const float* pB = lds + lrB * CCAP + lcB;
        f32x2 FX = {fxA, fxB};
        f32x2 FY = {fyA, fyB};

        size_t o = (size_t)h * W_ + w;

        // channel 0
        {
            f32x2 P00 = {pA[0],        pB[0]};
            f32x2 P10 = {pA[1],        pB[1]};
            f32x2 P01 = {pA[CCAP],     pB[CCAP]};
            f32x2 P11 = {pA[CCAP + 1], pB[CCAP + 1]};
            f32x2 top = (P10 - P00) * FX + P00;
            f32x2 bot = (P11 - P01) * FX + P01;
            f32x2 v   = (bot - top) * FY + top;
            *(float2*)(on + o) = make_float2(v.x, v.y);
        }
        // channel 1
        {
            f32x2 P00 = {pA[CH_STRIDE],            pB[CH_STRIDE]};
            f32x2 P10 = {pA[CH_STRIDE + 1],        pB[CH_STRIDE + 1]};
            f32x2 P01 = {pA[CH_STRIDE + CCAP],     pB[CH_STRIDE + CCAP]};
            f32x2 P11 = {pA[CH_STRIDE + CCAP + 1], pB[CH_STRIDE + CCAP + 1]};
            f32x2 top = (P10 - P00) * FX + P00;
            f32x2 bot = (P11 - P01) * FX + P01;
            f32x2 v   = (bot - top) * FY + top;
            *(float2*)(on + o + HW_) = make_float2(v.x, v.y);
        }
        // channel 2
        {
            f32x2 P00 = {pA[2 * CH_STRIDE],            pB[2 * CH_STRIDE]};
            f32x2 P10 = {pA[2 * CH_STRIDE + 1],        pB[2 * CH_STRIDE + 1]};
            f32x2 P01 = {pA[2 * CH_STRIDE + CCAP],     pB[2 * CH_STRIDE + CCAP]};
            f32x2 P11 = {pA[2 * CH_STRIDE + CCAP + 1], pB[2 * CH_STRIDE + CCAP + 1]};
            f32x2 top = (P10 - P00) * FX + P00;
            f32x2 bot = (P11 - P01) * FX + P01;
            f32x2 v   = (bot - top) * FY + top;
            *(float2*)(on + o + 2 * HW_) = make_float2(v.x, v.y);
        }
    } else {
        // ---- rare block-uniform wholesale path (theta-extreme): direct gather ----
        if (w >= W_ || h >= H_) return;        // no barrier on this path

        float fw = (float)w, fh = (float)h;
        float hx  = fmaf(fh, Bx, Cx), hy = fmaf(fh, By, Cy);
        float ixA = fmaf(fw, Ax, hx), iyA = fmaf(fw, Ay, hy);
        float ixB = ixA + Ax,         iyB = iyA + Ay;

        float xfA = floorf(ixA), yfA = floorf(iyA);
        float fxA = ixA - xfA,   fyA = iyA - yfA;
        int   XA  = (int)xfA,    YA  = (int)yfA;
        float xfB = floorf(ixB), yfB = floorf(iyB);
        float fxB = ixB - xfB,   fyB = iyB - yfB;
        int   XB  = (int)xfB,    YB  = (int)yfB;

        float gxA = 1.0f - fxA, gyA = 1.0f - fyA;
        float gxB = 1.0f - fxB, gyB = 1.0f - fyB;
        float wA00 = gxA * gyA, wA10 = fxA * gyA, wA01 = gxA * fyA, wA11 = fxA * fyA;
        float wB00 = gxB * gyB, wB10 = fxB * gyB, wB01 = gxB * fyB, wB11 = fxB * fyB;
        float vA0 = 0, vA1 = 0, vA2 = 0, vB0 = 0, vB1 = 0, vB2 = 0;
#define CORNG(xi, yi, wt, d0, d1, d2)                                         \
        if ((unsigned)(xi) < (unsigned)W_ && (unsigned)(yi) < (unsigned)H_) { \
            int off = (yi) * W_ + (xi);                                       \
            d0 += xn[off] * (wt);                                             \
            d1 += xn[HW_ + off] * (wt);                                       \
            d2 += xn[2 * HW_ + off] * (wt);                                   \
        }
        CORNG(XA,     YA,     wA00, vA0, vA1, vA2)
        CORNG(XA + 1, YA,     wA10, vA0, vA1, vA2)
        CORNG(XA,     YA + 1, wA01, vA0, vA1, vA2)
        CORNG(XA + 1, YA + 1, wA11, vA0, vA1, vA2)
        CORNG(XB,     YB,     wB00, vB0, vB1, vB2)
        CORNG(XB + 1, YB,     wB10, vB0, vB1, vB2)
        CORNG(XB,     YB + 1, wB01, vB0, vB1, vB2)
        CORNG(XB + 1, YB + 1, wB11, vB0, vB1, vB2)
#undef CORNG
        size_t o = (size_t)h * W_ + w;
        *(float2*)(on + o)           = make_float2(vA0, vB0);
        *(float2*)(on + o + HW_)     = make_float2(vA1, vB1);
        *(float2*)(on + o + 2 * HW_) = make_float2(vA2, vB2);
    }
}

extern "C" void kernel_launch(void* const* d_in, const int* in_sizes, int n_in,
                              void* d_out, int out_size, void* d_ws, size_t ws_size,
                              hipStream_t stream) {
    const float* x     = (const float*)d_in[0];
    const float* theta = (const float*)d_in[1];
    float* out = (float*)d_out;

    int blocks = N_ * TILES;   // 21120, divisible by 8
    gs_tiled<<<blocks, 256, 0, stream>>>(x, theta, out);
}

// Round 13
// 42.199 us; speedup vs baseline: 1.3097x; 1.0636x over previous
//
#include <hip/hip_runtime.h>

// affine_grid + grid_sample (bilinear, zeros, align_corners=False)
// N=64, C=3, H=345, W=456, fp32.
// Round 13: r12 structure (unclamped zero-filled window, no per-pixel checks)
//           + cheap clamp+select edge staging (whole-float4 granule validity)
//           + readfirstlane-scalarized uniforms.
constexpr int N_ = 64, C_ = 3, H_ = 345, W_ = 456;
constexpr int HW_ = H_ * W_;

constexpr int TW = 32, TH = 16;                // output tile: 512 px, 2 px/thread
constexpr int TX = 15, TY = 22;
constexpr int TILES = TX * TY;                 // 330
constexpr int CCAP = 52;                       // staged cols / LDS row stride (13 float4)
constexpr int RCAP = 28;                       // staged rows
constexpr int CJ   = 13;                       // float4 columns
constexpr int CH_STRIDE = RCAP * CCAP;         // 1456 floats/channel (17472 B total)
constexpr int SLOTS = CJ * RCAP;               // 364 float4 slots per channel

typedef __attribute__((ext_vector_type(2))) float f32x2;

__device__ __forceinline__ float ufl(float v) {
    return __int_as_float(__builtin_amdgcn_readfirstlane(__float_as_int(v)));
}

__global__ __launch_bounds__(256) void gs_tiled(
    const float* __restrict__ x,      // [N,3,H,W]
    const float* __restrict__ theta,  // [N,2,3]
    float* __restrict__ out)          // [N,3,H,W]
{
    __shared__ float lds[3 * CH_STRIDE];       // 17472 B

    // XCD-affine: batch n -> XCD n%8 only (grid divisible by 8).
    int b    = blockIdx.x;
    int xcd  = b & 7;
    int i    = b >> 3;
    int bg   = i / TILES;
    int tile = i - bg * TILES;
    int n    = xcd + 8 * bg;

    int ty = tile / TX;
    int tx = tile - ty * TX;
    int w0 = tx * TW, h0 = ty * TH;

    const float* t = theta + n * 6;
    float t00 = ufl(t[0]), t01 = ufl(t[1]), t02 = ufl(t[2]);
    float t10 = ufl(t[3]), t11 = ufl(t[4]), t12 = ufl(t[5]);

    const float halfW = 0.5f * (float)W_, cW = 0.5f * (float)(W_ - 1);
    const float halfH = 0.5f * (float)H_, cH = 0.5f * (float)(H_ - 1);
    const float startx = -(1.0f - 1.0f / (float)W_);
    const float starty = -(1.0f - 1.0f / (float)H_);

    // Linear map: ix = Ax*w + Bx*h + Cx ; iy = Ay*w + By*h + Cy
    float Ax = t00;
    float Bx = t01 * ((float)W_ / (float)H_);
    float Cx = fmaf(startx, t00, fmaf(starty, t01, t02)) * halfW + cW;
    float Ay = t10 * ((float)H_ / (float)W_);
    float By = t11;
    float Cy = fmaf(startx, t10, fmaf(starty, t11, t12)) * halfH + cH;

    // ---- exact source bbox over the clamped tile (linear map, monotone) ----
    float ws = (float)w0, we = (float)min(w0 + TW - 1, W_ - 1);
    float hs = (float)h0, he = (float)min(h0 + TH - 1, H_ - 1);

    float xw0 = ws * Ax, xw1 = we * Ax;
    float xh0 = hs * Bx, xh1 = he * Bx;
    float minix = Cx + fminf(xw0, xw1) + fminf(xh0, xh1);
    float maxix = Cx + fmaxf(xw0, xw1) + fmaxf(xh0, xh1);

    float yw0 = ws * Ay, yw1 = we * Ay;
    float yh0 = hs * By, yh1 = he * By;
    float miniy = Cy + fminf(yw0, yw1) + fminf(yh0, yh1);
    float maxiy = Cy + fmaxf(yw0, yw1) + fmaxf(yh0, yh1);

    // +-1 margin (fp slack); +1 more on hi for bilinear's +1 corner
    int x_lo = (int)floorf(minix) - 1, x_hi = (int)floorf(maxix) + 2;
    int y_lo = (int)floorf(miniy) - 1, y_hi = (int)floorf(maxiy) + 2;

    int xa    = x_lo & ~3;                     // align down (ok for negatives)
    int cols4 = (x_hi - xa + 4) >> 2;
    int rows  = y_hi - y_lo + 1;
    bool fits = (cols4 <= CJ) && (rows <= RCAP);   // block-uniform

    const float* xn = x + (size_t)n * 3 * HW_;
    float* on = out + (size_t)n * 3 * HW_;

    int tid = threadIdx.x;
    int tw = (tid & 15) * 2, th = tid >> 4;
    int w = w0 + tw, h = h0 + th;

    if (__builtin_expect(fits, 1)) {
        // ---- stage full CCAPxRCAP window at (xa, y_lo); zero-fill OOI ----
        bool interior = (xa >= 0) && (xa + CCAP <= W_) &&
                        (y_lo >= 0) && (y_lo + RCAP <= H_);
        int s1 = tid;
        int r1 = s1 / 13, j1 = s1 - 13 * r1;
        int s2 = tid + 256;
        int r2 = s2 / 13, j2 = s2 - 13 * r2;
        bool has2 = s2 < SLOTS;                // tid < 108

        if (interior) {
            // branch-free float4 staging
            const float* g1 = xn + (size_t)(y_lo + r1) * W_ + xa + 4 * j1;
            float4 a0 = *(const float4*)(g1);
            float4 a1 = *(const float4*)(g1 + HW_);
            float4 a2 = *(const float4*)(g1 + 2 * HW_);
            float* d1 = lds + 4 * s1;
            *(float4*)(d1)                 = a0;
            *(float4*)(d1 + CH_STRIDE)     = a1;
            *(float4*)(d1 + 2 * CH_STRIDE) = a2;

            if (has2) {
                const float* g2 = xn + (size_t)(y_lo + r2) * W_ + xa + 4 * j2;
                float4 b0 = *(const float4*)(g2);
                float4 b1 = *(const float4*)(g2 + HW_);
                float4 b2 = *(const float4*)(g2 + 2 * HW_);
                float* d2 = lds + 4 * s2;
                *(float4*)(d2)                 = b0;
                *(float4*)(d2 + CH_STRIDE)     = b1;
                *(float4*)(d2 + 2 * CH_STRIDE) = b2;
            }
        } else {
            // edge staging: clamped (always-legal) float4 load + whole-granule select.
            // xa%4==0 and W%4==0 => each float4 granule is entirely in or out in x.
            {
                int y  = y_lo + r1;
                int xc = xa + 4 * j1;
                int ycl = min(max(y, 0), H_ - 1);
                int xcl = min(max(xc, 0), W_ - 4);
                bool valid = ((unsigned)y < (unsigned)H_) && ((unsigned)xc <= (unsigned)(W_ - 4));
                const float* g1 = xn + (size_t)ycl * W_ + xcl;
                float4 a0 = *(const float4*)(g1);
                float4 a1 = *(const float4*)(g1 + HW_);
                float4 a2 = *(const float4*)(g1 + 2 * HW_);
                float4 z = make_float4(0.f, 0.f, 0.f, 0.f);
                if (!valid) { a0 = z; a1 = z; a2 = z; }
                float* d1 = lds + 4 * s1;
                *(float4*)(d1)                 = a0;
                *(float4*)(d1 + CH_STRIDE)     = a1;
                *(float4*)(d1 + 2 * CH_STRIDE) = a2;
            }
            if (has2) {
                int y  = y_lo + r2;
                int xc = xa + 4 * j2;
                int ycl = min(max(y, 0), H_ - 1);
                int xcl = min(max(xc, 0), W_ - 4);
                bool valid = ((unsigned)y < (unsigned)H_) && ((unsigned)xc <= (unsigned)(W_ - 4));
                const float* g2 = xn + (size_t)ycl * W_ + xcl;
                float4 b0 = *(const float4*)(g2);
                float4 b1 = *(const float4*)(g2 + HW_);
                float4 b2 = *(const float4*)(g2 + 2 * HW_);
                float4 z = make_float4(0.f, 0.f, 0.f, 0.f);
                if (!valid) { b0 = z; b1 = z; b2 = z; }
                float* d2 = lds + 4 * s2;
                *(float4*)(d2)                 = b0;
                *(float4*)(d2 + CH_STRIDE)     = b1;
                *(float4*)(d2 + 2 * CH_STRIDE) = b2;
            }
        }
        __syncthreads();

        if (w >= W_ || h >= H_) return;        // after the only barrier

        // ---- compute: NO window checks (bbox + zero-fill guarantee) ----
        float fw = (float)w, fh = (float)h;
        float hx  = fmaf(fh, Bx, Cx), hy = fmaf(fh, By, Cy);
        float ixA = fmaf(fw, Ax, hx), iyA = fmaf(fw, Ay, hy);
        float ixB = ixA + Ax,         iyB = iyA + Ay;

        float xfA = floorf(ixA), yfA = floorf(iyA);
        float fxA = ixA - xfA,   fyA = iyA - yfA;
        float xfB = floorf(ixB), yfB = floorf(iyB);
        float fxB = ixB - xfB,   fyB = iyB - yfB;

        int lcA = (int)xfA - xa, lrA = (int)yfA - y_lo;
        int lcB = (int)xfB - xa, lrB = (int)yfB - y_lo;

        const float* pA = lds + lrA * CCAP + lcA;
        const float* pB = lds + lrB * CCAP + lcB;
        f32x2 FX = {fxA, fxB};
        f32x2 FY = {fyA, fyB};

        size_t o = (size_t)h * W_ + w;

        // channel 0
        {
            f32x2 P00 = {pA[0],        pB[0]};
            f32x2 P10 = {pA[1],        pB[1]};
            f32x2 P01 = {pA[CCAP],     pB[CCAP]};
            f32x2 P11 = {pA[CCAP + 1], pB[CCAP + 1]};
            f32x2 top = (P10 - P00) * FX + P00;
            f32x2 bot = (P11 - P01) * FX + P01;
            f32x2 v   = (bot - top) * FY + top;
            *(float2*)(on + o) = make_float2(v.x, v.y);
        }
        // channel 1
        {
            f32x2 P00 = {pA[CH_STRIDE],            pB[CH_STRIDE]};
            f32x2 P10 = {pA[CH_STRIDE + 1],        pB[CH_STRIDE + 1]};
            f32x2 P01 = {pA[CH_STRIDE + CCAP],     pB[CH_STRIDE + CCAP]};
            f32x2 P11 = {pA[CH_STRIDE + CCAP + 1], pB[CH_STRIDE + CCAP + 1]};
            f32x2 top = (P10 - P00) * FX + P00;
            f32x2 bot = (P11 - P01) * FX + P01;
            f32x2 v   = (bot - top) * FY + top;
            *(float2*)(on + o + HW_) = make_float2(v.x, v.y);
        }
        // channel 2
        {
            f32x2 P00 = {pA[2 * CH_STRIDE],            pB[2 * CH_STRIDE]};
            f32x2 P10 = {pA[2 * CH_STRIDE + 1],        pB[2 * CH_STRIDE + 1]};
            f32x2 P01 = {pA[2 * CH_STRIDE + CCAP],     pB[2 * CH_STRIDE + CCAP]};
            f32x2 P11 = {pA[2 * CH_STRIDE + CCAP + 1], pB[2 * CH_STRIDE + CCAP + 1]};
            f32x2 top = (P10 - P00) * FX + P00;
            f32x2 bot = (P11 - P01) * FX + P01;
            f32x2 v   = (bot - top) * FY + top;
            *(float2*)(on + o + 2 * HW_) = make_float2(v.x, v.y);
        }
    } else {
        // ---- rare block-uniform wholesale path (theta-extreme): direct gather ----
        if (w >= W_ || h >= H_) return;        // no barrier on this path (block-uniform)

        float fw = (float)w, fh = (float)h;
        float hx  = fmaf(fh, Bx, Cx), hy = fmaf(fh, By, Cy);
        float ixA = fmaf(fw, Ax, hx), iyA = fmaf(fw, Ay, hy);
        float ixB = ixA + Ax,         iyB = iyA + Ay;

        float xfA = floorf(ixA), yfA = floorf(iyA);
        float fxA = ixA - xfA,   fyA = iyA - yfA;
        int   XA  = (int)xfA,    YA  = (int)yfA;
        float xfB = floorf(ixB), yfB = floorf(iyB);
        float fxB = ixB - xfB,   fyB = iyB - yfB;
        int   XB  = (int)xfB,    YB  = (int)yfB;

        float gxA = 1.0f - fxA, gyA = 1.0f - fyA;
        float gxB = 1.0f - fxB, gyB = 1.0f - fyB;
        float wA00 = gxA * gyA, wA10 = fxA * gyA, wA01 = gxA * fyA, wA11 = fxA * fyA;
        float wB00 = gxB * gyB, wB10 = fxB * gyB, wB01 = gxB * fyB, wB11 = fxB * fyB;
        float vA0 = 0, vA1 = 0, vA2 = 0, vB0 = 0, vB1 = 0, vB2 = 0;
#define CORNG(xi, yi, wt, d0, d1, d2)                                         \
        if ((unsigned)(xi) < (unsigned)W_ && (unsigned)(yi) < (unsigned)H_) { \
            int off = (yi) * W_ + (xi);                                       \
            d0 += xn[off] * (wt);                                             \
            d1 += xn[HW_ + off] * (wt);                                       \
            d2 += xn[2 * HW_ + off] * (wt);                                   \
        }
        CORNG(XA,     YA,     wA00, vA0, vA1, vA2)
        CORNG(XA + 1, YA,     wA10, vA0, vA1, vA2)
        CORNG(XA,     YA + 1, wA01, vA0, vA1, vA2)
        CORNG(XA + 1, YA + 1, wA11, vA0, vA1, vA2)
        CORNG(XB,     YB,     wB00, vB0, vB1, vB2)
        CORNG(XB + 1, YB,     wB10, vB0, vB1, vB2)
        CORNG(XB,     YB + 1, wB01, vB0, vB1, vB2)
        CORNG(XB + 1, YB + 1, wB11, vB0, vB1, vB2)
#undef CORNG
        size_t o = (size_t)h * W_ + w;
        *(float2*)(on + o)           = make_float2(vA0, vB0);
        *(float2*)(on + o + HW_)     = make_float2(vA1, vB1);
        *(float2*)(on + o + 2 * HW_) = make_float2(vA2, vB2);
    }
}

extern "C" void kernel_launch(void* const* d_in, const int* in_sizes, int n_in,
                              void* d_out, int out_size, void* d_ws, size_t ws_size,
                              hipStream_t stream) {
    const float* x     = (const float*)d_in[0];
    const float* theta = (const float*)d_in[1];
    float* out = (float*)d_out;

    int blocks = N_ * TILES;   // 21120, divisible by 8
    gs_tiled<<<blocks, 256, 0, stream>>>(x, theta, out);
}